// Round 7
// baseline (3750.839 us; speedup 1.0000x reference)
//
#include <hip/hip_runtime.h>
#include <cstdint>
#include <cstddef>

#define BB 512   // batch
#define TT 512   // seq len
#define HH 100   // hidden
#define G4 400   // 4*H

// ---------------------------------------------------------------------------
// Recurrent kernel: full 512 steps of one layer in one launch.
// grid = 256 blocks x 448 threads, 1 block/CU. Block owns elems {2*bid, 2*bid+1}.
// Thread map: j = tid>>2 (unit, active j<100), g = tid&3:
//   pair = g>>1: 0 -> rows (i_j, g_j) = (j, 200+j); 1 -> (f_j, o_j) = (100+j, 300+j)
//   par  = g&1:  k-half for the dot ([0,48) | [48,100)) AND owned elem after reduce.
// Weights: 2 rows x 52-float k-window = 104 VGPRs (lo lanes zero-pad k48..51).
// h lives in LDS interleaved [k][elem] so ONE broadcast ds_read_b128 feeds
// 2 k x 2 elems -> 26 reads + 208 FMA per step per thread (8 FMA per read).
// Reduce: shfl_xor(1) x2 completes own-elem sums; activations in-lane;
// shfl_xor(2) ships sig(i)*tanh(g) to the (f,o) lane which owns c/h.
// One __syncthreads per step; h double-buffered. No LDS weight staging
// (1.8 KB LDS total) -> no AGPR parking (the round-5/6 killer: 200 floats
// over the 128 arch-VGPR heuristic got parked in AGPRs, 1 accvgpr_read/FMA).
// ---------------------------------------------------------------------------
template<bool IS_L0, bool WRITE_DROP>
__global__ __launch_bounds__(448, 1)
void rec_kernel(const float* __restrict__ x,       // [B][T] (layer0 input, IN=1)
                const float* __restrict__ xc,      // [T][B][400] (layers>0)
                const float* __restrict__ Whh_l,   // [400][100]
                const float* __restrict__ Wih0,    // [400] (layer0)
                const float* __restrict__ bih_l,   // [400] (layer0)
                const float* __restrict__ bhh_l,   // [400] (layer0)
                const float* __restrict__ dmask_l, // [B][T][100] (if WRITE_DROP)
                float* __restrict__ hdrop,         // [T][B][100] (if WRITE_DROP)
                float* __restrict__ st_h,          // [B][100]
                float* __restrict__ st_c)          // [B][100]
{
    __shared__ float hbuf[2][112][2];   // [buf][k][elem] interleaved, 1792 B

    const int tid  = threadIdx.x;
    const int j    = tid >> 2;                 // 0..111 (unit)
    const int g    = tid & 3;
    const int pair = g >> 1;                   // 0: (i,g) rows  1: (f,o) rows
    const int par  = g & 1;                    // k-half / owned elem
    const bool active = (j < HH);
    const int jc   = active ? j : (HH - 1);
    const int rA   = pair * 100 + jc;          // i or f row (sigmoid)
    const int rB   = rA + 200;                 // g or o row
    const int b    = blockIdx.x * 2 + par;     // owned batch elem
    const bool isFO = (pair == 1);

    // --- weights: 52-float k-window of rows rA, rB straight from global ---
    float wA[52], wB[52];
    {
        const int kb = par * 48;
        const float4* pa = (const float4*)(Whh_l + (size_t)rA * HH + kb);
        const float4* pb = (const float4*)(Whh_l + (size_t)rB * HH + kb);
        const int nf = 12 + par;               // lo: 12 real float4s, hi: 13
        #pragma unroll
        for (int m = 0; m < 13; ++m) {
            float4 va = {0.f, 0.f, 0.f, 0.f};
            float4 vb = {0.f, 0.f, 0.f, 0.f};
            if (m < nf) { va = pa[m]; vb = pb[m]; }
            wA[4 * m + 0] = va.x; wA[4 * m + 1] = va.y;
            wA[4 * m + 2] = va.z; wA[4 * m + 3] = va.w;
            wB[4 * m + 0] = vb.x; wB[4 * m + 1] = vb.y;
            wB[4 * m + 2] = vb.z; wB[4 * m + 3] = vb.w;
        }
    }

    float wxA = 0.f, wxB = 0.f, bsA = 0.f, bsB = 0.f;
    if (IS_L0) {
        wxA = Wih0[rA];  bsA = bih_l[rA] + bhh_l[rA];
        wxB = Wih0[rB];  bsB = bih_l[rB] + bhh_l[rB];
    }

    // zero both h buffers incl. k-padding (448 floats, one per thread)
    ((float*)hbuf)[tid] = 0.f;

    float c2 = 0.f, hlast = 0.f;
    __syncthreads();

    // --- prefetch t = 0 ---
    float ginA = 0.f, ginB = 0.f, xv = 0.f, mk = 0.f;
    if (IS_L0) {
        xv = x[(size_t)b * TT];
    } else {
        ginA = xc[(size_t)b * G4 + rA];
        ginB = xc[(size_t)b * G4 + rB];
    }
    if (WRITE_DROP && isFO && active) mk = dmask_l[(size_t)b * TT * HH + jc];

    int cur = 0;
    for (int t = 0; t < TT; ++t) {
        const int tn = (t + 1 < TT) ? (t + 1) : t;

        // --- issue prefetches for t+1 ---
        float nxv = 0.f, nginA = 0.f, nginB = 0.f, nmk = 0.f;
        if (IS_L0) {
            nxv = x[(size_t)b * TT + tn];
        } else {
            const size_t base = (size_t)tn * (BB * G4) + (size_t)b * G4;
            nginA = xc[base + rA];
            nginB = xc[base + rB];
        }
        if (WRITE_DROP && isFO && active)
            nmk = dmask_l[((size_t)b * TT + tn) * HH + jc];

        if (IS_L0) {
            ginA = fmaf(xv, wxA, bsA);
            ginB = fmaf(xv, wxB, bsB);
        }

        // --- dot over k-window for both elems (broadcast b128 reads) ---
        float aA0 = 0.f, aA1 = 0.f, aB0 = 0.f, aB1 = 0.f;
        {
            const float4* hp4 = (const float4*)&hbuf[cur][par * 48][0];
            #pragma unroll
            for (int m = 0; m < 26; ++m) {
                const float4 hv = hp4[m];   // h[k][e0], h[k][e1], h[k+1][e0], h[k+1][e1]
                aA0 = fmaf(wA[2 * m],     hv.x, aA0);
                aA1 = fmaf(wA[2 * m],     hv.y, aA1);
                aB0 = fmaf(wB[2 * m],     hv.x, aB0);
                aB1 = fmaf(wB[2 * m],     hv.y, aB1);
                aA0 = fmaf(wA[2 * m + 1], hv.z, aA0);
                aA1 = fmaf(wA[2 * m + 1], hv.w, aA1);
                aB0 = fmaf(wB[2 * m + 1], hv.z, aB0);
                aB1 = fmaf(wB[2 * m + 1], hv.w, aB1);
            }
        }

        // --- cross-k-half reduce: complete own-elem sums on this lane ---
        const float sendA = par ? aA0 : aA1;
        const float keepA = par ? aA1 : aA0;
        const float totA  = keepA + __shfl_xor(sendA, 1) + ginA;   // i | f preact
        const float sendB = par ? aB0 : aB1;
        const float keepB = par ? aB1 : aB0;
        const float totB  = keepB + __shfl_xor(sendB, 1) + ginB;   // g | o preact

        // --- activations: sA = sig(i|f); actB = tanh(g) | sig(o) ---
        const float eA   = __expf(-totA);
        const float sA   = 1.f / (1.f + eA);
        const float eB   = __expf(isFO ? (-totB) : (totB + totB));
        const float rB_  = 1.f / (1.f + eB);
        const float actB = isFO ? rB_ : fmaf(-2.f, rB_, 1.f);

        // pair0 ships sig(i)*tanh(g) to its (f,o) partner (lane^2)
        const float ship  = sA * actB;
        const float recvP = __shfl_xor(ship, 2);

        const int nxt = cur ^ 1;
        if (isFO) {
            c2 = fmaf(sA, c2, recvP);                 // c = sig(f)*c + sig(i)*tanh(g)
            const float Ec = __expf(c2 + c2);
            const float th = 1.f - 2.f / (Ec + 1.f);  // tanh(c)
            const float h  = actB * th;               // sig(o)*tanh(c)
            hlast = h;
            if (active) {
                hbuf[nxt][j][par] = h;
                if (WRITE_DROP)
                    hdrop[((size_t)t * BB + b) * HH + j] = h * mk * 2.f;
            }
        }
        __syncthreads();
        cur = nxt;
        ginA = nginA; ginB = nginB; xv = nxv; mk = nmk;
    }

    if (isFO && active) {
        st_h[(size_t)b * HH + j] = hlast;
        st_c[(size_t)b * HH + j] = c2;
    }
}

// ---------------------------------------------------------------------------
// Input-contribution GEMM for layers 1..3 (measured ~280us/launch):
// xc[m][n] = sum_k A[m][k]*W[n][k] + (bih[n]+bhh[n]), M=T*B=262144, N=400,K=100
// tile 128(M)x64(N), 256 threads, 8x4 microtile, LDS 80 KB -> 2 blocks/CU.
// ---------------------------------------------------------------------------
__global__ __launch_bounds__(256, 2)
void xc_gemm(const float* __restrict__ A,     // [M][100]
             const float* __restrict__ W,     // [400][100]
             const float* __restrict__ bih_l, // [400]
             const float* __restrict__ bhh_l, // [400]
             float* __restrict__ xc)          // [M][400]
{
    __shared__ float At[HH][132];
    __shared__ float Bt[HH][68];

    const int tid = threadIdx.x;
    const int n0  = blockIdx.x * 64;
    const size_t m0 = (size_t)blockIdx.y * 128;

    for (int s = tid; s < 128 * 25; s += 256) {
        const int r = s / 25, kq = s - r * 25;
        const float4 v = *(const float4*)&A[(m0 + r) * HH + kq * 4];
        At[kq * 4 + 0][r] = v.x; At[kq * 4 + 1][r] = v.y;
        At[kq * 4 + 2][r] = v.z; At[kq * 4 + 3][r] = v.w;
    }
    for (int s = tid; s < 64 * 25; s += 256) {
        const int r = s / 25, kq = s - r * 25;
        const int col = n0 + r;
        float4 v = {0.f, 0.f, 0.f, 0.f};
        if (col < G4) v = *(const float4*)&W[(size_t)col * HH + kq * 4];
        Bt[kq * 4 + 0][r] = v.x; Bt[kq * 4 + 1][r] = v.y;
        Bt[kq * 4 + 2][r] = v.z; Bt[kq * 4 + 3][r] = v.w;
    }
    __syncthreads();

    const int tx = tid & 15;   // col group: cols tx*4..+3
    const int ty = tid >> 4;   // row group: rows ty*8..+7
    float acc[8][4];
    #pragma unroll
    for (int i = 0; i < 8; ++i)
        #pragma unroll
        for (int jj = 0; jj < 4; ++jj) acc[i][jj] = 0.f;

    #pragma unroll 4
    for (int k = 0; k < HH; ++k) {
        const float4 a0 = *(const float4*)&At[k][ty * 8];
        const float4 a1 = *(const float4*)&At[k][ty * 8 + 4];
        const float4 bv = *(const float4*)&Bt[k][tx * 4];
        const float av[8] = {a0.x, a0.y, a0.z, a0.w, a1.x, a1.y, a1.z, a1.w};
        #pragma unroll
        for (int i = 0; i < 8; ++i) {
            acc[i][0] = fmaf(av[i], bv.x, acc[i][0]);
            acc[i][1] = fmaf(av[i], bv.y, acc[i][1]);
            acc[i][2] = fmaf(av[i], bv.z, acc[i][2]);
            acc[i][3] = fmaf(av[i], bv.w, acc[i][3]);
        }
    }

    const int col = n0 + tx * 4;
    if (col < G4) {
        const float4 u = *(const float4*)&bih_l[col];
        const float4 v = *(const float4*)&bhh_l[col];
        const float4 bias = {u.x + v.x, u.y + v.y, u.z + v.z, u.w + v.w};
        #pragma unroll
        for (int i = 0; i < 8; ++i) {
            const size_t r = m0 + ty * 8 + i;
            float4 o = {acc[i][0] + bias.x, acc[i][1] + bias.y,
                        acc[i][2] + bias.z, acc[i][3] + bias.w};
            *(float4*)&xc[r * G4 + col] = o;
        }
    }
}

// ---------------------------------------------------------------------------
__global__ __launch_bounds__(256)
void out_kernel(const float* __restrict__ st_h3,  // [B][100]
                const float* __restrict__ Wout,   // [100]
                const float* __restrict__ bout,   // [1]
                float* __restrict__ out)          // [B]
{
    const int b = blockIdx.x * 256 + threadIdx.x;
    if (b < BB) {
        float sum = bout[0];
        #pragma unroll 4
        for (int k = 0; k < HH; ++k)
            sum = fmaf(st_h3[(size_t)b * HH + k], Wout[k], sum);
        out[b] = sum;
    }
}

// ---------------------------------------------------------------------------
extern "C" void kernel_launch(void* const* d_in, const int* in_sizes, int n_in,
                              void* d_out, int out_size, void* d_ws, size_t ws_size,
                              hipStream_t stream)
{
    const float* x     = (const float*)d_in[0];  // [512][512][1]
    const float* Wih0  = (const float*)d_in[1];  // [400][1]
    const float* WihR  = (const float*)d_in[2];  // [3][400][100]
    const float* Whh   = (const float*)d_in[3];  // [4][400][100]
    const float* bih   = (const float*)d_in[4];  // [4][400]
    const float* bhh   = (const float*)d_in[5];  // [4][400]
    const float* Wout  = (const float*)d_in[6];  // [1][100]
    const float* bout  = (const float*)d_in[7];  // [1]
    const float* dmask = (const float*)d_in[8];  // [3][512][512][100]
    float* out = (float*)d_out;

    // ws layout (floats): ~526 MB of the 1200 MB workspace
    float* ws    = (float*)d_ws;
    float* xcb   = ws;                                  // T*B*400
    float* hdrop = xcb + (size_t)TT * BB * G4;          // T*B*100
    float* sth   = hdrop + (size_t)TT * BB * HH;        // 4*B*100
    float* stc   = sth + (size_t)4 * BB * HH;           // 4*B*100

    const dim3 rgrid(BB / 2), rblk(448);
    const dim3 ggrid(7, (TT * BB) / 128), gblk(256);

    // layer 0 (input dim 1 fused into rec)
    rec_kernel<true, true><<<rgrid, rblk, 0, stream>>>(
        x, nullptr, Whh, Wih0, bih, bhh, dmask,
        hdrop, sth, stc);
    // layers 1..3
    for (int l = 1; l < 4; ++l) {
        xc_gemm<<<ggrid, gblk, 0, stream>>>(
            hdrop, WihR + (size_t)(l - 1) * G4 * HH,
            bih + l * G4, bhh + l * G4, xcb);
        if (l < 3) {
            rec_kernel<false, true><<<rgrid, rblk, 0, stream>>>(
                nullptr, xcb, Whh + (size_t)l * G4 * HH,
                nullptr, nullptr, nullptr,
                dmask + (size_t)l * BB * TT * HH,
                hdrop, sth + (size_t)l * BB * HH, stc + (size_t)l * BB * HH);
        } else {
            rec_kernel<false, false><<<rgrid, rblk, 0, stream>>>(
                nullptr, xcb, Whh + (size_t)l * G4 * HH,
                nullptr, nullptr, nullptr,
                nullptr,
                nullptr, sth + (size_t)l * BB * HH, stc + (size_t)l * BB * HH);
        }
    }
    out_kernel<<<dim3(2), dim3(256), 0, stream>>>(sth + (size_t)3 * BB * HH, Wout, bout, out);
}